// Round 4
// baseline (629.326 us; speedup 1.0000x reference)
//
#include <hip/hip_runtime.h>
#include <math.h>

#define D 128
#define BLOCKS 704   // capacity with __launch_bounds__(256,3) is 768: all co-resident
#define THREADS 256
#define NW (BLOCKS * 4)

typedef short s8v __attribute__((ext_vector_type(8)));
typedef float f4v __attribute__((ext_vector_type(4)));

__device__ __forceinline__ float fast_tanh(float z) {
    float e = __expf(2.f * z);
    return 1.f - 2.f / (e + 1.f);
}
__device__ __forceinline__ unsigned cvt_pk_bf16(float lo, float hi) {
    unsigned r;
    asm("v_cvt_pk_bf16_f32 %0, %1, %2" : "=v"(r) : "v"(lo), "v"(hi));
    return r;
}
__device__ __forceinline__ s8v pack8(float4 w0, float4 w1) {
    union { unsigned u[4]; s8v v; } r;
    r.u[0] = cvt_pk_bf16(w0.x, w0.y);
    r.u[1] = cvt_pk_bf16(w0.z, w0.w);
    r.u[2] = cvt_pk_bf16(w1.x, w1.y);
    r.u[3] = cvt_pk_bf16(w1.z, w1.w);
    return r.v;
}
__device__ __forceinline__ float bf_lo(unsigned w) {
    union { unsigned u; float f; } v; v.u = w << 16; return v.f;
}
__device__ __forceinline__ float bf_hi(unsigned w) {
    union { unsigned u; float f; } v; v.u = w & 0xffff0000u; return v.f;
}

// Device-scope grid barrier. Release: threadfence + ACQ_REL arrival add
// (flushes this XCD's dirty L2 lines -> coherence point). Spin: RELAXED
// agent loads (coherence-point reads, NO repeated L2 invalidation that
// would thrash still-running blocks). Pass: one ACQUIRE load invalidates
// this CU's L1 / XCD's L2 so subsequent plain reads are fresh (G16).
__device__ __forceinline__ void gridBarrier(unsigned* c, unsigned nblk) {
    __syncthreads();
    if (threadIdx.x == 0) {
        __threadfence();
        __hip_atomic_fetch_add(c, 1u, __ATOMIC_ACQ_REL, __HIP_MEMORY_SCOPE_AGENT);
        unsigned v;
        do {
            __builtin_amdgcn_s_sleep(2);
            v = __hip_atomic_load(c, __ATOMIC_RELAXED, __HIP_MEMORY_SCOPE_AGENT);
        } while (v < nblk);
        (void)__hip_atomic_load(c, __ATOMIC_ACQUIRE, __HIP_MEMORY_SCOPE_AGENT);
    }
    __syncthreads();
}

// Cross-quad reduce then ONE atomic per address (128 ops, 1-way).
#define RFLUSH(ACC_, SEG_, DST_)                                              \
    if ((SEG_) >= 0) {                                                        \
        _Pragma("unroll")                                                     \
        for (int t = 0; t < 8; ++t) {                                         \
            ACC_[t] += __shfl_xor(ACC_[t], 16);                               \
            ACC_[t] += __shfl_xor(ACC_[t], 32);                               \
        }                                                                     \
        _Pragma("unroll")                                                     \
        for (int t = 0; t < 8; ++t)                                           \
            if ((t >> 1) == quad)                                             \
                atomicAdd(&(DST_)[(size_t)(SEG_) * 128 + m15 + 16 * t], ACC_[t]); \
    }

// Phase A epilogue for one C-row-group RG_: y = x*(1+tanh(z)), y -> x2s bf16
// (coalesced uint4, same layout phase C reads), y bucketed tl/th/direct.
#define EPI0(RG_)                                                             \
    {                                                                         \
        int r = R + quad * 4 + RG_;                                           \
        int seg = batch[r];                                                   \
        const float* xrow = x + (size_t)r * 128 + m15;                        \
        float yv[8];                                                          \
        _Pragma("unroll")                                                     \
        for (int t = 0; t < 8; ++t) {                                         \
            float z = af[t][RG_] + b2l[t];                                    \
            yv[t] = xrow[16 * t] * (1.f + fast_tanh(z));                      \
        }                                                                     \
        union { unsigned u[4]; uint4 q; } pk;                                 \
        pk.u[0] = cvt_pk_bf16(yv[0], yv[1]);                                  \
        pk.u[1] = cvt_pk_bf16(yv[2], yv[3]);                                  \
        pk.u[2] = cvt_pk_bf16(yv[4], yv[5]);                                  \
        pk.u[3] = cvt_pk_bf16(yv[6], yv[7]);                                  \
        ((uint4*)x2s)[(size_t)b * 256 + RG_ * 64 + lane] = pk.q;              \
        if (seg == segLo) {                                                   \
            _Pragma("unroll")                                                 \
            for (int t = 0; t < 8; ++t) tl[t] += yv[t];                       \
        } else if (seg == segHi) {                                            \
            _Pragma("unroll")                                                 \
            for (int t = 0; t < 8; ++t) th[t] += yv[t];                       \
        } else {                                                              \
            _Pragma("unroll")                                                 \
            for (int t = 0; t < 8; ++t)                                       \
                atomicAdd(&sums[(size_t)seg * 128 + m15 + 16 * t], yv[t]);    \
        }                                                                     \
    }

// Fused A+B+C: one dispatch, two grid barriers.
__global__ __launch_bounds__(THREADS, 3) void fusedABC(
    const float* __restrict__ x, const int* __restrict__ batch,
    const float* __restrict__ fc1_w, const float* __restrict__ fc1_b,
    const float* __restrict__ fc2_w, const float* __restrict__ fc2_b,
    const float* __restrict__ Wm, float* __restrict__ sums,
    float* __restrict__ tg, unsigned short* __restrict__ x2s,
    unsigned* __restrict__ ctr, float* __restrict__ out, int N, int B)
{
    __shared__ s8v wB1[2][4][64];       // GEMM1 B-fragments, 8 KB
    __shared__ s8v wB2[8][64];          // GEMM2 B-fragments, 8 KB
    __shared__ float hbuf[4][16 * 36];  // wave-private scratch (h / mean row)

    const int lane = threadIdx.x & 63;
    const int wv = threadIdx.x >> 6;
    const int m15 = lane & 15;
    const int quad = lane >> 4;

    if (wv == 0) {
        #pragma unroll
        for (int t = 0; t < 2; ++t)
            #pragma unroll
            for (int kc = 0; kc < 4; ++kc) {
                const float* p = fc1_w + (16 * t + m15) * 128 + kc * 32 + quad * 8;
                wB1[t][kc][lane] = pack8(*(const float4*)p, *(const float4*)(p + 4));
            }
        #pragma unroll
        for (int t = 0; t < 8; ++t) {
            const float* p = fc2_w + (16 * t + m15) * 32 + quad * 8;
            wB2[t][lane] = pack8(*(const float4*)p, *(const float4*)(p + 4));
        }
    }
    float b1l[2], b2l[8];
    #pragma unroll
    for (int t = 0; t < 2; ++t) b1l[t] = fc1_b[m15 + 16 * t];
    #pragma unroll
    for (int t = 0; t < 8; ++t) b2l[t] = fc2_b[m15 + 16 * t];
    __syncthreads();

    const int total16 = N >> 4;
    const int gw = blockIdx.x * 4 + wv;
    const int base = total16 / NW, rem = total16 % NW;
    const int b0 = gw * base + (gw < rem ? gw : rem);
    const int b1e = b0 + base + (gw < rem ? 1 : 0);

    float* hw = hbuf[wv];
    const f4v z4 = {0.f, 0.f, 0.f, 0.f};

    // ================= PHASE A =================
    {
        float accW[8];
        #pragma unroll
        for (int t = 0; t < 8; ++t) accW[t] = 0.f;
        int curW = -1;

        float4 F[8];
        if (b0 < b1e) {
            const float* xp = x + (size_t)(b0 << 4) * D + m15 * 128 + quad * 8;
            #pragma unroll
            for (int kc = 0; kc < 4; ++kc) {
                F[2 * kc]     = *(const float4*)(xp + kc * 32);
                F[2 * kc + 1] = *(const float4*)(xp + kc * 32 + 4);
            }
        }

        for (int b = b0; b < b1e; ++b) {
            const int R = b << 4;
            s8v ax[4];
            #pragma unroll
            for (int kc = 0; kc < 4; ++kc)
                ax[kc] = pack8(F[2 * kc], F[2 * kc + 1]);
            if (b + 1 < b1e) {
                const float* xp = x + (size_t)((b + 1) << 4) * D + m15 * 128 + quad * 8;
                #pragma unroll
                for (int kc = 0; kc < 4; ++kc) {
                    F[2 * kc]     = *(const float4*)(xp + kc * 32);
                    F[2 * kc + 1] = *(const float4*)(xp + kc * 32 + 4);
                }
            }
            f4v accH[2];
            accH[0] = z4; accH[1] = z4;
            #pragma unroll
            for (int kc = 0; kc < 4; ++kc) {
                accH[0] = __builtin_amdgcn_mfma_f32_16x16x32_bf16(ax[kc], wB1[0][kc][lane], accH[0], 0, 0, 0);
                accH[1] = __builtin_amdgcn_mfma_f32_16x16x32_bf16(ax[kc], wB1[1][kc][lane], accH[1], 0, 0, 0);
            }
            #pragma unroll
            for (int t = 0; t < 2; ++t)
                #pragma unroll
                for (int rg = 0; rg < 4; ++rg) {
                    float hv = fmaxf(accH[t][rg] + b1l[t], 0.f);
                    hw[(quad * 4 + rg) * 36 + m15 + 16 * t] = hv;
                }
            const f4v h0 = *(const f4v*)&hw[m15 * 36 + quad * 8];
            const f4v h1 = *(const f4v*)&hw[m15 * 36 + quad * 8 + 4];
            union { unsigned u[4]; s8v v; } ahu;
            ahu.u[0] = cvt_pk_bf16(h0[0], h0[1]);
            ahu.u[1] = cvt_pk_bf16(h0[2], h0[3]);
            ahu.u[2] = cvt_pk_bf16(h1[0], h1[1]);
            ahu.u[3] = cvt_pk_bf16(h1[2], h1[3]);
            s8v ah = ahu.v;
            f4v af[8];
            #pragma unroll
            for (int t = 0; t < 8; ++t)
                af[t] = __builtin_amdgcn_mfma_f32_16x16x32_bf16(ah, wB2[t][lane], z4, 0, 0, 0);

            const int segLo = batch[R];
            const int segHi = batch[R + 15];
            float tl[8], th[8];
            #pragma unroll
            for (int t = 0; t < 8; ++t) { tl[t] = 0.f; th[t] = 0.f; }

            EPI0(0) EPI0(1) EPI0(2) EPI0(3)

            if (segLo == curW) {
                #pragma unroll
                for (int t = 0; t < 8; ++t) accW[t] += tl[t];
            } else {
                RFLUSH(accW, curW, sums)
                curW = segLo;
                #pragma unroll
                for (int t = 0; t < 8; ++t) accW[t] = tl[t];
            }
            if (segHi != segLo) {
                RFLUSH(accW, curW, sums)
                curW = segHi;
                #pragma unroll
                for (int t = 0; t < 8; ++t) accW[t] = th[t];
            }
        }
        RFLUSH(accW, curW, sums)
    }

    // zero 'out' (poisoned each iteration); must precede barrier 1
    {
        const int tot = B * D;
        for (int i = blockIdx.x * THREADS + threadIdx.x; i < tot; i += BLOCKS * THREADS)
            out[i] = 0.f;
    }

    gridBarrier(&ctr[0], BLOCKS);

    // ================= PHASE B ================= (one wave per segment)
    if (gw < B) {
        const int s = gw;
        int lo0 = 0, hi0 = N;
        while (lo0 < hi0) { int mid = (lo0 + hi0) >> 1; if (batch[mid] < s) lo0 = mid + 1; else hi0 = mid; }
        int lo1 = lo0, hi1 = N;
        while (lo1 < hi1) { int mid = (lo1 + hi1) >> 1; if (batch[mid] < s + 1) lo1 = mid + 1; else hi1 = mid; }
        float invc = 1.f / fmaxf((float)(lo1 - lo0), 1.f);
        hw[lane]      = sums[(size_t)s * 128 + lane] * invc;
        hw[lane + 64] = sums[(size_t)s * 128 + lane + 64] * invc;
        float a0 = 0.f, a1 = 0.f;
        #pragma unroll 8
        for (int k = 0; k < D; ++k) {
            float mk = hw[k];
            a0 = fmaf(mk, Wm[(size_t)k * 128 + lane], a0);
            a1 = fmaf(mk, Wm[(size_t)k * 128 + lane + 64], a1);
        }
        tg[(size_t)s * 128 + lane]      = fast_tanh(a0);
        tg[(size_t)s * 128 + lane + 64] = fast_tanh(a1);
    }

    gridBarrier(&ctr[1], BLOCKS);

    // ================= PHASE C =================
    {
        float accW[8], tgv[8];
        #pragma unroll
        for (int t = 0; t < 8; ++t) { accW[t] = 0.f; tgv[t] = 0.f; }
        int curW = -1, curT = -1;

        for (int b = b0; b < b1e; ++b) {
            const int R = b << 4;
            const uint4* p = (const uint4*)x2s + (size_t)b * 256 + lane;
            uint4 C0 = p[0], C1 = p[64], C2 = p[128], C3 = p[192];
            const int segLo = batch[R];
            const int segHi = batch[R + 15];
            float tl[8], th[8];
            #pragma unroll
            for (int t = 0; t < 8; ++t) { tl[t] = 0.f; th[t] = 0.f; }

            #pragma unroll
            for (int rg = 0; rg < 4; ++rg) {
                uint4 C = rg == 0 ? C0 : rg == 1 ? C1 : rg == 2 ? C2 : C3;
                int seg = batch[R + quad * 4 + rg];
                if (seg != curT) {
                    curT = seg;
                    #pragma unroll
                    for (int t = 0; t < 8; ++t)
                        tgv[t] = tg[(size_t)seg * 128 + m15 + 16 * t];
                }
                float xv[8];
                xv[0] = bf_lo(C.x); xv[1] = bf_hi(C.x);
                xv[2] = bf_lo(C.y); xv[3] = bf_hi(C.y);
                xv[4] = bf_lo(C.z); xv[5] = bf_hi(C.z);
                xv[6] = bf_lo(C.w); xv[7] = bf_hi(C.w);
                float dot = 0.f;
                #pragma unroll
                for (int t = 0; t < 8; ++t) dot = fmaf(xv[t], tgv[t], dot);
                dot += __shfl_xor(dot, 1);
                dot += __shfl_xor(dot, 2);
                dot += __shfl_xor(dot, 4);
                dot += __shfl_xor(dot, 8);
                float coef = 1.f / (1.f + __expf(-dot));
                if (seg == segLo) {
                    #pragma unroll
                    for (int t = 0; t < 8; ++t) tl[t] = fmaf(coef, xv[t], tl[t]);
                } else if (seg == segHi) {
                    #pragma unroll
                    for (int t = 0; t < 8; ++t) th[t] = fmaf(coef, xv[t], th[t]);
                } else {
                    #pragma unroll
                    for (int t = 0; t < 8; ++t)
                        atomicAdd(&out[(size_t)seg * 128 + m15 + 16 * t], coef * xv[t]);
                }
            }

            if (segLo == curW) {
                #pragma unroll
                for (int t = 0; t < 8; ++t) accW[t] += tl[t];
            } else {
                RFLUSH(accW, curW, out)
                curW = segLo;
                #pragma unroll
                for (int t = 0; t < 8; ++t) accW[t] = tl[t];
            }
            if (segHi != segLo) {
                RFLUSH(accW, curW, out)
                curW = segHi;
                #pragma unroll
                for (int t = 0; t < 8; ++t) accW[t] = th[t];
            }
        }
        RFLUSH(accW, curW, out)
    }
}

extern "C" void kernel_launch(void* const* d_in, const int* in_sizes, int n_in,
                              void* d_out, int out_size, void* d_ws, size_t ws_size,
                              hipStream_t stream) {
    const float* x     = (const float*)d_in[0];
    const int*   batch = (const int*)d_in[1];
    const float* Wm    = (const float*)d_in[3];
    const float* fc1_w = (const float*)d_in[4];
    const float* fc1_b = (const float*)d_in[5];
    const float* fc2_w = (const float*)d_in[6];
    const float* fc2_b = (const float*)d_in[7];
    float* out = (float*)d_out;

    int N = in_sizes[0] / D;
    int B = out_size / D;

    // ws layout: sums[B*D] f32 | ctr[16] u32 | tg[B*D] f32 | x2s[N*D] bf16
    float* sums = (float*)d_ws;
    unsigned* ctr = (unsigned*)((char*)d_ws + (size_t)B * D * 4);
    float* tg = (float*)((char*)ctr + 64);
    unsigned short* x2s = (unsigned short*)(tg + (size_t)B * D);

    // zero sums + barrier counters (one small memset); out zeroed in-kernel
    hipMemsetAsync(d_ws, 0, (size_t)B * D * 4 + 64, stream);

    fusedABC<<<BLOCKS, THREADS, 0, stream>>>(
        x, batch, fc1_w, fc1_b, fc2_w, fc2_b, Wm,
        sums, tg, x2s, ctr, out, N, B);
}

// Round 5
// 564.220 us; speedup vs baseline: 1.1154x; 1.1154x over previous
//
#include <hip/hip_runtime.h>
#include <math.h>

#define D 128
#define BLOCKS_A 1536  // 6 blocks/CU co-resident with __launch_bounds__(256,6); VGPR<=85 (fused measured 80)
#define BLOCKS_C 1536  // same: 24 waves/CU for the streaming phase
#define THREADS 256

typedef short s8v __attribute__((ext_vector_type(8)));
typedef float f4v __attribute__((ext_vector_type(4)));

__device__ __forceinline__ float fast_tanh(float z) {
    float e = __expf(2.f * z);
    return 1.f - 2.f / (e + 1.f);
}
__device__ __forceinline__ unsigned cvt_pk_bf16(float lo, float hi) {
    unsigned r;
    asm("v_cvt_pk_bf16_f32 %0, %1, %2" : "=v"(r) : "v"(lo), "v"(hi));
    return r;
}
__device__ __forceinline__ s8v pack8(float4 w0, float4 w1) {
    union { unsigned u[4]; s8v v; } r;
    r.u[0] = cvt_pk_bf16(w0.x, w0.y);
    r.u[1] = cvt_pk_bf16(w0.z, w0.w);
    r.u[2] = cvt_pk_bf16(w1.x, w1.y);
    r.u[3] = cvt_pk_bf16(w1.z, w1.w);
    return r.v;
}
__device__ __forceinline__ float bf_lo(unsigned w) {
    union { unsigned u; float f; } v; v.u = w << 16; return v.f;
}
__device__ __forceinline__ float bf_hi(unsigned w) {
    union { unsigned u; float f; } v; v.u = w & 0xffff0000u; return v.f;
}

// Cross-quad reduce then ONE atomic per address (128 ops, 1-way).
#define RFLUSH(ACC_, SEG_, DST_)                                              \
    if ((SEG_) >= 0) {                                                        \
        _Pragma("unroll")                                                     \
        for (int t = 0; t < 8; ++t) {                                         \
            ACC_[t] += __shfl_xor(ACC_[t], 16);                               \
            ACC_[t] += __shfl_xor(ACC_[t], 32);                               \
        }                                                                     \
        _Pragma("unroll")                                                     \
        for (int t = 0; t < 8; ++t)                                           \
            if ((t >> 1) == quad)                                             \
                atomicAdd(&(DST_)[(size_t)(SEG_) * 128 + m15 + 16 * t], ACC_[t]); \
    }

// Phase A epilogue for one C-row-group RG_: y = x*(1+tanh(z)), y -> x2s bf16
// (coalesced uint4, same layout phase C reads), y bucketed tl/th/direct.
#define EPI0(RG_)                                                             \
    {                                                                         \
        int r = R + quad * 4 + RG_;                                           \
        int seg = batch[r];                                                   \
        const float* xrow = x + (size_t)r * 128 + m15;                        \
        float yv[8];                                                          \
        _Pragma("unroll")                                                     \
        for (int t = 0; t < 8; ++t) {                                         \
            float z = af[t][RG_] + b2l[t];                                    \
            yv[t] = xrow[16 * t] * (1.f + fast_tanh(z));                      \
        }                                                                     \
        union { unsigned u[4]; uint4 q; } pk;                                 \
        pk.u[0] = cvt_pk_bf16(yv[0], yv[1]);                                  \
        pk.u[1] = cvt_pk_bf16(yv[2], yv[3]);                                  \
        pk.u[2] = cvt_pk_bf16(yv[4], yv[5]);                                  \
        pk.u[3] = cvt_pk_bf16(yv[6], yv[7]);                                  \
        ((uint4*)x2s)[(size_t)b * 256 + RG_ * 64 + lane] = pk.q;              \
        if (seg == segLo) {                                                   \
            _Pragma("unroll")                                                 \
            for (int t = 0; t < 8; ++t) tl[t] += yv[t];                       \
        } else if (seg == segHi) {                                            \
            _Pragma("unroll")                                                 \
            for (int t = 0; t < 8; ++t) th[t] += yv[t];                       \
        } else {                                                              \
            _Pragma("unroll")                                                 \
            for (int t = 0; t < 8; ++t)                                       \
                atomicAdd(&sums[(size_t)seg * 128 + m15 + 16 * t], yv[t]);    \
        }                                                                     \
    }

// Phase A: x2 = x*(1+tanh(MLP(x))); wave-level segment sums; x2 cached bf16.
__global__ __launch_bounds__(THREADS, 6) void phaseA(
    const float* __restrict__ x, const int* __restrict__ batch,
    const float* __restrict__ fc1_w, const float* __restrict__ fc1_b,
    const float* __restrict__ fc2_w, const float* __restrict__ fc2_b,
    float* __restrict__ sums, unsigned short* __restrict__ x2s, int N)
{
    __shared__ s8v wB1[2][4][64];       // GEMM1 B-fragments, 8 KB
    __shared__ s8v wB2[8][64];          // GEMM2 B-fragments, 8 KB
    __shared__ float hbuf[4][16 * 36];  // f32 hidden, pitch 36, wave-private

    const int lane = threadIdx.x & 63;
    const int wv = threadIdx.x >> 6;
    const int m15 = lane & 15;
    const int quad = lane >> 4;

    if (wv == 0) {
        #pragma unroll
        for (int t = 0; t < 2; ++t)
            #pragma unroll
            for (int kc = 0; kc < 4; ++kc) {
                const float* p = fc1_w + (16 * t + m15) * 128 + kc * 32 + quad * 8;
                wB1[t][kc][lane] = pack8(*(const float4*)p, *(const float4*)(p + 4));
            }
        #pragma unroll
        for (int t = 0; t < 8; ++t) {
            const float* p = fc2_w + (16 * t + m15) * 32 + quad * 8;
            wB2[t][lane] = pack8(*(const float4*)p, *(const float4*)(p + 4));
        }
    }
    float b1l[2], b2l[8];
    #pragma unroll
    for (int t = 0; t < 2; ++t) b1l[t] = fc1_b[m15 + 16 * t];
    #pragma unroll
    for (int t = 0; t < 8; ++t) b2l[t] = fc2_b[m15 + 16 * t];
    __syncthreads();

    const int total16 = N >> 4;
    const int nw = BLOCKS_A * 4;
    const int gw = blockIdx.x * 4 + wv;
    const int base = total16 / nw, rem = total16 % nw;
    const int b0 = gw * base + (gw < rem ? gw : rem);
    const int b1e = b0 + base + (gw < rem ? 1 : 0);

    float* hw = hbuf[wv];

    float accW[8];
    #pragma unroll
    for (int t = 0; t < 8; ++t) accW[t] = 0.f;
    int curW = -1;
    const f4v z4 = {0.f, 0.f, 0.f, 0.f};

    // software pipeline: F holds the in-flight x tile in MFMA A-layout
    float4 F[8];
    if (b0 < b1e) {
        const float* xp = x + (size_t)(b0 << 4) * D + m15 * 128 + quad * 8;
        #pragma unroll
        for (int kc = 0; kc < 4; ++kc) {
            F[2 * kc]     = *(const float4*)(xp + kc * 32);
            F[2 * kc + 1] = *(const float4*)(xp + kc * 32 + 4);
        }
    }

    for (int b = b0; b < b1e; ++b) {
        const int R = b << 4;
        s8v ax[4];
        #pragma unroll
        for (int kc = 0; kc < 4; ++kc)
            ax[kc] = pack8(F[2 * kc], F[2 * kc + 1]);
        if (b + 1 < b1e) {
            const float* xp = x + (size_t)((b + 1) << 4) * D + m15 * 128 + quad * 8;
            #pragma unroll
            for (int kc = 0; kc < 4; ++kc) {
                F[2 * kc]     = *(const float4*)(xp + kc * 32);
                F[2 * kc + 1] = *(const float4*)(xp + kc * 32 + 4);
            }
        }
        // GEMM1: h[16][32] = x @ W1^T
        f4v accH[2];
        accH[0] = z4; accH[1] = z4;
        #pragma unroll
        for (int kc = 0; kc < 4; ++kc) {
            accH[0] = __builtin_amdgcn_mfma_f32_16x16x32_bf16(ax[kc], wB1[0][kc][lane], accH[0], 0, 0, 0);
            accH[1] = __builtin_amdgcn_mfma_f32_16x16x32_bf16(ax[kc], wB1[1][kc][lane], accH[1], 0, 0, 0);
        }
        #pragma unroll
        for (int t = 0; t < 2; ++t)
            #pragma unroll
            for (int rg = 0; rg < 4; ++rg) {
                float hv = fmaxf(accH[t][rg] + b1l[t], 0.f);
                hw[(quad * 4 + rg) * 36 + m15 + 16 * t] = hv;
            }
        const f4v h0 = *(const f4v*)&hw[m15 * 36 + quad * 8];
        const f4v h1 = *(const f4v*)&hw[m15 * 36 + quad * 8 + 4];
        union { unsigned u[4]; s8v v; } ahu;
        ahu.u[0] = cvt_pk_bf16(h0[0], h0[1]);
        ahu.u[1] = cvt_pk_bf16(h0[2], h0[3]);
        ahu.u[2] = cvt_pk_bf16(h1[0], h1[1]);
        ahu.u[3] = cvt_pk_bf16(h1[2], h1[3]);
        s8v ah = ahu.v;
        // GEMM2: a[16][128] = h @ W2^T
        f4v af[8];
        #pragma unroll
        for (int t = 0; t < 8; ++t)
            af[t] = __builtin_amdgcn_mfma_f32_16x16x32_bf16(ah, wB2[t][lane], z4, 0, 0, 0);

        // ---- epilogue with wave-level segment buckets ----
        const int segLo = batch[R];
        const int segHi = batch[R + 15];
        float tl[8], th[8];
        #pragma unroll
        for (int t = 0; t < 8; ++t) { tl[t] = 0.f; th[t] = 0.f; }

        EPI0(0) EPI0(1) EPI0(2) EPI0(3)

        if (segLo == curW) {
            #pragma unroll
            for (int t = 0; t < 8; ++t) accW[t] += tl[t];
        } else {
            RFLUSH(accW, curW, sums)
            curW = segLo;
            #pragma unroll
            for (int t = 0; t < 8; ++t) accW[t] = tl[t];
        }
        if (segHi != segLo) {
            RFLUSH(accW, curW, sums)
            curW = segHi;
            #pragma unroll
            for (int t = 0; t < 8; ++t) accW[t] = th[t];
        }
    }
    RFLUSH(accW, curW, sums)
}

// tg = tanh((sums/count) @ Wm); counts from binary search on sorted batch.
__global__ __launch_bounds__(D, 8) void phaseB(
    const float* __restrict__ sums, const int* __restrict__ batch,
    const float* __restrict__ Wm, float* __restrict__ tg, int N)
{
    int b = blockIdx.x;
    int d = threadIdx.x;
    __shared__ float m[D];
    __shared__ int bnd[2];
    if (d < 2) {
        int target = b + d;
        int lo = 0, hi = N;
        while (lo < hi) {
            int mid = (lo + hi) >> 1;
            if (batch[mid] < target) lo = mid + 1; else hi = mid;
        }
        bnd[d] = lo;
    }
    __syncthreads();
    float inv = 1.f / fmaxf((float)(bnd[1] - bnd[0]), 1.f);
    m[d] = sums[(b << 7) + d] * inv;
    __syncthreads();
    float acc = 0.f;
    #pragma unroll 8
    for (int k = 0; k < D; ++k)
        acc = fmaf(m[k], Wm[(k << 7) + d], acc);
    tg[(b << 7) + d] = fast_tanh(acc);
}

// Phase C: stream cached x2 (bf16), coef = sigmoid(<x2, tg[seg]>),
// out += coef*x2 with wave-level bucket flush.
__global__ __launch_bounds__(THREADS, 6) void phaseC(
    const unsigned short* __restrict__ x2s, const int* __restrict__ batch,
    const float* __restrict__ tg, float* __restrict__ out, int N)
{
    const int lane = threadIdx.x & 63;
    const int wv = threadIdx.x >> 6;
    const int m15 = lane & 15;
    const int quad = lane >> 4;

    const int total16 = N >> 4;
    const int nw = BLOCKS_C * 4;
    const int gw = blockIdx.x * 4 + wv;
    const int base = total16 / nw, rem = total16 % nw;
    const int b0 = gw * base + (gw < rem ? gw : rem);
    const int b1e = b0 + base + (gw < rem ? 1 : 0);

    float accW[8], tgv[8];
    #pragma unroll
    for (int t = 0; t < 8; ++t) { accW[t] = 0.f; tgv[t] = 0.f; }
    int curW = -1;
    int curT = -1;

    for (int b = b0; b < b1e; ++b) {
        const int R = b << 4;
        const uint4* p = (const uint4*)x2s + (size_t)b * 256 + lane;
        uint4 C0 = p[0], C1 = p[64], C2 = p[128], C3 = p[192];
        const int segLo = batch[R];
        const int segHi = batch[R + 15];
        float tl[8], th[8];
        #pragma unroll
        for (int t = 0; t < 8; ++t) { tl[t] = 0.f; th[t] = 0.f; }

        #pragma unroll
        for (int rg = 0; rg < 4; ++rg) {
            uint4 C = rg == 0 ? C0 : rg == 1 ? C1 : rg == 2 ? C2 : C3;
            int seg = batch[R + quad * 4 + rg];
            if (seg != curT) {
                curT = seg;
                #pragma unroll
                for (int t = 0; t < 8; ++t)
                    tgv[t] = tg[(size_t)seg * 128 + m15 + 16 * t];
            }
            float xv[8];
            xv[0] = bf_lo(C.x); xv[1] = bf_hi(C.x);
            xv[2] = bf_lo(C.y); xv[3] = bf_hi(C.y);
            xv[4] = bf_lo(C.z); xv[5] = bf_hi(C.z);
            xv[6] = bf_lo(C.w); xv[7] = bf_hi(C.w);
            float dot = 0.f;
            #pragma unroll
            for (int t = 0; t < 8; ++t) dot = fmaf(xv[t], tgv[t], dot);
            dot += __shfl_xor(dot, 1);
            dot += __shfl_xor(dot, 2);
            dot += __shfl_xor(dot, 4);
            dot += __shfl_xor(dot, 8);
            float coef = 1.f / (1.f + __expf(-dot));
            if (seg == segLo) {
                #pragma unroll
                for (int t = 0; t < 8; ++t) tl[t] = fmaf(coef, xv[t], tl[t]);
            } else if (seg == segHi) {
                #pragma unroll
                for (int t = 0; t < 8; ++t) th[t] = fmaf(coef, xv[t], th[t]);
            } else {
                #pragma unroll
                for (int t = 0; t < 8; ++t)
                    atomicAdd(&out[(size_t)seg * 128 + m15 + 16 * t], coef * xv[t]);
            }
        }

        if (segLo == curW) {
            #pragma unroll
            for (int t = 0; t < 8; ++t) accW[t] += tl[t];
        } else {
            RFLUSH(accW, curW, out)
            curW = segLo;
            #pragma unroll
            for (int t = 0; t < 8; ++t) accW[t] = tl[t];
        }
        if (segHi != segLo) {
            RFLUSH(accW, curW, out)
            curW = segHi;
            #pragma unroll
            for (int t = 0; t < 8; ++t) accW[t] = th[t];
        }
    }
    RFLUSH(accW, curW, out)
}

extern "C" void kernel_launch(void* const* d_in, const int* in_sizes, int n_in,
                              void* d_out, int out_size, void* d_ws, size_t ws_size,
                              hipStream_t stream) {
    const float* x     = (const float*)d_in[0];
    const int*   batch = (const int*)d_in[1];
    const float* Wm    = (const float*)d_in[3];
    const float* fc1_w = (const float*)d_in[4];
    const float* fc1_b = (const float*)d_in[5];
    const float* fc2_w = (const float*)d_in[6];
    const float* fc2_b = (const float*)d_in[7];
    float* out = (float*)d_out;

    int N = in_sizes[0] / D;
    int B = out_size / D;

    float* sums = (float*)d_ws;                        // [B,128]
    float* tg   = sums + (size_t)B * D;                // [B,128]
    unsigned short* x2s = (unsigned short*)(tg + (size_t)B * D); // [N,128] bf16

    hipMemsetAsync(d_ws, 0, (size_t)B * D * sizeof(float), stream);
    hipMemsetAsync(d_out, 0, (size_t)out_size * sizeof(float), stream);

    phaseA<<<BLOCKS_A, THREADS, 0, stream>>>(
        x, batch, fc1_w, fc1_b, fc2_w, fc2_b, sums, x2s, N);
    phaseB<<<B, D, 0, stream>>>(sums, batch, Wm, tg, N);
    phaseC<<<BLOCKS_C, THREADS, 0, stream>>>(x2s, batch, tg, out, N);
}

// Round 6
// 438.858 us; speedup vs baseline: 1.4340x; 1.2857x over previous
//
#include <hip/hip_runtime.h>
#include <math.h>

#define D 128
#define BLOCKS_A 768   // 3 blocks/CU (LDS 42KB/block caps at 3); bounds(256,3) -> no VGPR squeeze/spill
#define BLOCKS_C 1536
#define THREADS 256

typedef short s8v __attribute__((ext_vector_type(8)));
typedef float f4v __attribute__((ext_vector_type(4)));

__device__ __forceinline__ float fast_tanh(float z) {
    float e = __expf(2.f * z);
    return 1.f - 2.f / (e + 1.f);
}
__device__ __forceinline__ unsigned cvt_pk_bf16(float lo, float hi) {
    unsigned r;
    asm("v_cvt_pk_bf16_f32 %0, %1, %2" : "=v"(r) : "v"(lo), "v"(hi));
    return r;
}
__device__ __forceinline__ s8v pack8(float4 w0, float4 w1) {
    union { unsigned u[4]; s8v v; } r;
    r.u[0] = cvt_pk_bf16(w0.x, w0.y);
    r.u[1] = cvt_pk_bf16(w0.z, w0.w);
    r.u[2] = cvt_pk_bf16(w1.x, w1.y);
    r.u[3] = cvt_pk_bf16(w1.z, w1.w);
    return r.v;
}
__device__ __forceinline__ float bf2f(unsigned short h) {
    union { unsigned u; float f; } v; v.u = ((unsigned)h) << 16; return v.f;
}
__device__ __forceinline__ float bf_lo(unsigned w) {
    union { unsigned u; float f; } v; v.u = w << 16; return v.f;
}
__device__ __forceinline__ float bf_hi(unsigned w) {
    union { unsigned u; float f; } v; v.u = w & 0xffff0000u; return v.f;
}

// Cross-quad reduce then ONE atomic per address (128 ops, 1-way).
#define RFLUSH(ACC_, SEG_, DST_)                                              \
    if ((SEG_) >= 0) {                                                        \
        _Pragma("unroll")                                                     \
        for (int t = 0; t < 8; ++t) {                                         \
            ACC_[t] += __shfl_xor(ACC_[t], 16);                               \
            ACC_[t] += __shfl_xor(ACC_[t], 32);                               \
        }                                                                     \
        _Pragma("unroll")                                                     \
        for (int t = 0; t < 8; ++t)                                           \
            if ((t >> 1) == quad)                                             \
                atomicAdd(&(DST_)[(size_t)(SEG_) * 128 + m15 + 16 * t], ACC_[t]); \
    }

// Phase A epilogue for one C-row-group RG_: x read from wave-private LDS
// (C-layout; staged once this tile — no global re-fetch), y = x*(1+tanh(z)),
// y -> x2s bf16 (coalesced uint4, same layout phase C reads), y bucketed.
#define EPI0(RG_)                                                             \
    {                                                                         \
        int r = R + quad * 4 + RG_;                                           \
        int seg = batch[r];                                                   \
        float yv[8];                                                          \
        _Pragma("unroll")                                                     \
        for (int t = 0; t < 8; ++t) {                                         \
            float xf = bf2f(xw[(quad * 4 + RG_) * 136 + m15 + 16 * t]);       \
            float z = af[t][RG_] + b2l[t];                                    \
            yv[t] = xf * (1.f + fast_tanh(z));                                \
        }                                                                     \
        union { unsigned u[4]; uint4 q; } pk;                                 \
        pk.u[0] = cvt_pk_bf16(yv[0], yv[1]);                                  \
        pk.u[1] = cvt_pk_bf16(yv[2], yv[3]);                                  \
        pk.u[2] = cvt_pk_bf16(yv[4], yv[5]);                                  \
        pk.u[3] = cvt_pk_bf16(yv[6], yv[7]);                                  \
        ((uint4*)x2s)[(size_t)b * 256 + RG_ * 64 + lane] = pk.q;              \
        if (seg == segLo) {                                                   \
            _Pragma("unroll")                                                 \
            for (int t = 0; t < 8; ++t) tl[t] += yv[t];                       \
        } else if (seg == segHi) {                                            \
            _Pragma("unroll")                                                 \
            for (int t = 0; t < 8; ++t) th[t] += yv[t];                       \
        } else {                                                              \
            _Pragma("unroll")                                                 \
            for (int t = 0; t < 8; ++t)                                       \
                atomicAdd(&sums[(size_t)seg * 128 + m15 + 16 * t], yv[t]);    \
        }                                                                     \
    }

// Phase A: x2 = x*(1+tanh(MLP(x))); wave-level segment sums; x2 cached bf16.
// x staged to LDS once per tile (bf16): serves MFMA A-fragments AND the
// epilogue C-layout reads -> x fetched from HBM exactly once.
__global__ __launch_bounds__(THREADS, 3) void phaseA(
    const float* __restrict__ x, const int* __restrict__ batch,
    const float* __restrict__ fc1_w, const float* __restrict__ fc1_b,
    const float* __restrict__ fc2_w, const float* __restrict__ fc2_b,
    float* __restrict__ sums, unsigned short* __restrict__ x2s, int N)
{
    __shared__ unsigned short xbf[4][16 * 136]; // bf16 x rows, pitch 136, wave-private
    __shared__ s8v wB1[2][4][64];               // GEMM1 B-fragments, 8 KB
    __shared__ s8v wB2[8][64];                  // GEMM2 B-fragments, 8 KB
    __shared__ float hbuf[4][16 * 36];          // f32 hidden, pitch 36, wave-private

    const int lane = threadIdx.x & 63;
    const int wv = threadIdx.x >> 6;
    const int m15 = lane & 15;
    const int quad = lane >> 4;

    if (wv == 0) {
        #pragma unroll
        for (int t = 0; t < 2; ++t)
            #pragma unroll
            for (int kc = 0; kc < 4; ++kc) {
                const float* p = fc1_w + (16 * t + m15) * 128 + kc * 32 + quad * 8;
                wB1[t][kc][lane] = pack8(*(const float4*)p, *(const float4*)(p + 4));
            }
        #pragma unroll
        for (int t = 0; t < 8; ++t) {
            const float* p = fc2_w + (16 * t + m15) * 32 + quad * 8;
            wB2[t][lane] = pack8(*(const float4*)p, *(const float4*)(p + 4));
        }
    }
    float b1l[2], b2l[8];
    #pragma unroll
    for (int t = 0; t < 2; ++t) b1l[t] = fc1_b[m15 + 16 * t];
    #pragma unroll
    for (int t = 0; t < 8; ++t) b2l[t] = fc2_b[m15 + 16 * t];
    __syncthreads();

    const int total16 = N >> 4;
    const int nw = BLOCKS_A * 4;
    const int gw = blockIdx.x * 4 + wv;
    const int base = total16 / nw, rem = total16 % nw;
    const int b0 = gw * base + (gw < rem ? gw : rem);
    const int b1e = b0 + base + (gw < rem ? 1 : 0);

    unsigned short* xw = xbf[wv];
    float* hw = hbuf[wv];

    float accW[8];
    #pragma unroll
    for (int t = 0; t < 8; ++t) accW[t] = 0.f;
    int curW = -1;
    const f4v z4 = {0.f, 0.f, 0.f, 0.f};

    // software pipeline: L holds the in-flight x tile (coalesced row-major)
    float4 L[8];
    if (b0 < b1e) {
        const float* xp = x + (size_t)(b0 << 4) * D;
        #pragma unroll
        for (int u = 0; u < 8; ++u)
            L[u] = *(const float4*)(xp + u * 256 + lane * 4);
    }

    for (int b = b0; b < b1e; ++b) {
        const int R = b << 4;
        // convert arrived tile (frees L), then issue next-tile loads
        uint2 P[8];
        #pragma unroll
        for (int u = 0; u < 8; ++u) {
            P[u].x = cvt_pk_bf16(L[u].x, L[u].y);
            P[u].y = cvt_pk_bf16(L[u].z, L[u].w);
        }
        if (b + 1 < b1e) {
            const float* xp = x + (size_t)((b + 1) << 4) * D;
            #pragma unroll
            for (int u = 0; u < 8; ++u)
                L[u] = *(const float4*)(xp + u * 256 + lane * 4);
        }
        // stage bf16 tile to LDS (row = 2u + lane>>5, col = (lane&31)*4)
        #pragma unroll
        for (int u = 0; u < 8; ++u) {
            int row = 2 * u + (lane >> 5);
            int col = (lane & 31) * 4;
            *(uint2*)&xw[row * 136 + col] = P[u];
        }
        // A-fragments of x from LDS
        s8v ax[4];
        #pragma unroll
        for (int kc = 0; kc < 4; ++kc)
            ax[kc] = *(const s8v*)&xw[m15 * 136 + kc * 32 + quad * 8];
        // GEMM1: h[16][32] = x @ W1^T
        f4v accH[2];
        accH[0] = z4; accH[1] = z4;
        #pragma unroll
        for (int kc = 0; kc < 4; ++kc) {
            accH[0] = __builtin_amdgcn_mfma_f32_16x16x32_bf16(ax[kc], wB1[0][kc][lane], accH[0], 0, 0, 0);
            accH[1] = __builtin_amdgcn_mfma_f32_16x16x32_bf16(ax[kc], wB1[1][kc][lane], accH[1], 0, 0, 0);
        }
        #pragma unroll
        for (int t = 0; t < 2; ++t)
            #pragma unroll
            for (int rg = 0; rg < 4; ++rg) {
                float hv = fmaxf(accH[t][rg] + b1l[t], 0.f);
                hw[(quad * 4 + rg) * 36 + m15 + 16 * t] = hv;
            }
        const f4v h0 = *(const f4v*)&hw[m15 * 36 + quad * 8];
        const f4v h1 = *(const f4v*)&hw[m15 * 36 + quad * 8 + 4];
        union { unsigned u[4]; s8v v; } ahu;
        ahu.u[0] = cvt_pk_bf16(h0[0], h0[1]);
        ahu.u[1] = cvt_pk_bf16(h0[2], h0[3]);
        ahu.u[2] = cvt_pk_bf16(h1[0], h1[1]);
        ahu.u[3] = cvt_pk_bf16(h1[2], h1[3]);
        s8v ah = ahu.v;
        // GEMM2: a[16][128] = h @ W2^T
        f4v af[8];
        #pragma unroll
        for (int t = 0; t < 8; ++t)
            af[t] = __builtin_amdgcn_mfma_f32_16x16x32_bf16(ah, wB2[t][lane], z4, 0, 0, 0);

        // ---- epilogue with wave-level segment buckets ----
        const int segLo = batch[R];
        const int segHi = batch[R + 15];
        float tl[8], th[8];
        #pragma unroll
        for (int t = 0; t < 8; ++t) { tl[t] = 0.f; th[t] = 0.f; }

        EPI0(0) EPI0(1) EPI0(2) EPI0(3)

        if (segLo == curW) {
            #pragma unroll
            for (int t = 0; t < 8; ++t) accW[t] += tl[t];
        } else {
            RFLUSH(accW, curW, sums)
            curW = segLo;
            #pragma unroll
            for (int t = 0; t < 8; ++t) accW[t] = tl[t];
        }
        if (segHi != segLo) {
            RFLUSH(accW, curW, sums)
            curW = segHi;
            #pragma unroll
            for (int t = 0; t < 8; ++t) accW[t] = th[t];
        }
    }
    RFLUSH(accW, curW, sums)
}

// tg = tanh((sums/count) @ Wm); counts from binary search on sorted batch.
__global__ __launch_bounds__(D, 8) void phaseB(
    const float* __restrict__ sums, const int* __restrict__ batch,
    const float* __restrict__ Wm, float* __restrict__ tg, int N)
{
    int b = blockIdx.x;
    int d = threadIdx.x;
    __shared__ float m[D];
    __shared__ int bnd[2];
    if (d < 2) {
        int target = b + d;
        int lo = 0, hi = N;
        while (lo < hi) {
            int mid = (lo + hi) >> 1;
            if (batch[mid] < target) lo = mid + 1; else hi = mid;
        }
        bnd[d] = lo;
    }
    __syncthreads();
    float inv = 1.f / fmaxf((float)(bnd[1] - bnd[0]), 1.f);
    m[d] = sums[(b << 7) + d] * inv;
    __syncthreads();
    float acc = 0.f;
    #pragma unroll 8
    for (int k = 0; k < D; ++k)
        acc = fmaf(m[k], Wm[(k << 7) + d], acc);
    tg[(b << 7) + d] = fast_tanh(acc);
}

// Phase C: stream cached x2 (bf16), coef = sigmoid(<x2, tg[seg]>),
// out += coef*x2 with wave-level bucket flush.
__global__ __launch_bounds__(THREADS, 4) void phaseC(
    const unsigned short* __restrict__ x2s, const int* __restrict__ batch,
    const float* __restrict__ tg, float* __restrict__ out, int N)
{
    const int lane = threadIdx.x & 63;
    const int wv = threadIdx.x >> 6;
    const int m15 = lane & 15;
    const int quad = lane >> 4;

    const int total16 = N >> 4;
    const int nw = BLOCKS_C * 4;
    const int gw = blockIdx.x * 4 + wv;
    const int base = total16 / nw, rem = total16 % nw;
    const int b0 = gw * base + (gw < rem ? gw : rem);
    const int b1e = b0 + base + (gw < rem ? 1 : 0);

    float accW[8], tgv[8];
    #pragma unroll
    for (int t = 0; t < 8; ++t) { accW[t] = 0.f; tgv[t] = 0.f; }
    int curW = -1;
    int curT = -1;

    for (int b = b0; b < b1e; ++b) {
        const int R = b << 4;
        const uint4* p = (const uint4*)x2s + (size_t)b * 256 + lane;
        uint4 C0 = p[0], C1 = p[64], C2 = p[128], C3 = p[192];
        const int segLo = batch[R];
        const int segHi = batch[R + 15];
        float tl[8], th[8];
        #pragma unroll
        for (int t = 0; t < 8; ++t) { tl[t] = 0.f; th[t] = 0.f; }

        #pragma unroll
        for (int rg = 0; rg < 4; ++rg) {
            uint4 C = rg == 0 ? C0 : rg == 1 ? C1 : rg == 2 ? C2 : C3;
            int seg = batch[R + quad * 4 + rg];
            if (seg != curT) {
                curT = seg;
                #pragma unroll
                for (int t = 0; t < 8; ++t)
                    tgv[t] = tg[(size_t)seg * 128 + m15 + 16 * t];
            }
            float xv[8];
            xv[0] = bf_lo(C.x); xv[1] = bf_hi(C.x);
            xv[2] = bf_lo(C.y); xv[3] = bf_hi(C.y);
            xv[4] = bf_lo(C.z); xv[5] = bf_hi(C.z);
            xv[6] = bf_lo(C.w); xv[7] = bf_hi(C.w);
            float dot = 0.f;
            #pragma unroll
            for (int t = 0; t < 8; ++t) dot = fmaf(xv[t], tgv[t], dot);
            dot += __shfl_xor(dot, 1);
            dot += __shfl_xor(dot, 2);
            dot += __shfl_xor(dot, 4);
            dot += __shfl_xor(dot, 8);
            float coef = 1.f / (1.f + __expf(-dot));
            if (seg == segLo) {
                #pragma unroll
                for (int t = 0; t < 8; ++t) tl[t] = fmaf(coef, xv[t], tl[t]);
            } else if (seg == segHi) {
                #pragma unroll
                for (int t = 0; t < 8; ++t) th[t] = fmaf(coef, xv[t], th[t]);
            } else {
                #pragma unroll
                for (int t = 0; t < 8; ++t)
                    atomicAdd(&out[(size_t)seg * 128 + m15 + 16 * t], coef * xv[t]);
            }
        }

        if (segLo == curW) {
            #pragma unroll
            for (int t = 0; t < 8; ++t) accW[t] += tl[t];
        } else {
            RFLUSH(accW, curW, out)
            curW = segLo;
            #pragma unroll
            for (int t = 0; t < 8; ++t) accW[t] = tl[t];
        }
        if (segHi != segLo) {
            RFLUSH(accW, curW, out)
            curW = segHi;
            #pragma unroll
            for (int t = 0; t < 8; ++t) accW[t] = th[t];
        }
    }
    RFLUSH(accW, curW, out)
}

extern "C" void kernel_launch(void* const* d_in, const int* in_sizes, int n_in,
                              void* d_out, int out_size, void* d_ws, size_t ws_size,
                              hipStream_t stream) {
    const float* x     = (const float*)d_in[0];
    const int*   batch = (const int*)d_in[1];
    const float* Wm    = (const float*)d_in[3];
    const float* fc1_w = (const float*)d_in[4];
    const float* fc1_b = (const float*)d_in[5];
    const float* fc2_w = (const float*)d_in[6];
    const float* fc2_b = (const float*)d_in[7];
    float* out = (float*)d_out;

    int N = in_sizes[0] / D;
    int B = out_size / D;

    float* sums = (float*)d_ws;                        // [B,128]
    float* tg   = sums + (size_t)B * D;                // [B,128]
    unsigned short* x2s = (unsigned short*)(tg + (size_t)B * D); // [N,128] bf16

    hipMemsetAsync(d_ws, 0, (size_t)B * D * sizeof(float), stream);
    hipMemsetAsync(d_out, 0, (size_t)out_size * sizeof(float), stream);

    phaseA<<<BLOCKS_A, THREADS, 0, stream>>>(
        x, batch, fc1_w, fc1_b, fc2_w, fc2_b, sums, x2s, N);
    phaseB<<<B, D, 0, stream>>>(sums, batch, Wm, tg, N);
    phaseC<<<BLOCKS_C, THREADS, 0, stream>>>(x2s, batch, tg, out, N);
}

// Round 7
// 425.950 us; speedup vs baseline: 1.4775x; 1.0303x over previous
//
#include <hip/hip_runtime.h>
#include <math.h>

#define D 128
#define BLOCKS_A 768   // 3 blocks/CU (LDS 42KB/block caps at 3); bounds(256,3) -> no VGPR squeeze/spill
#define THREADS 256

typedef short s8v __attribute__((ext_vector_type(8)));
typedef float f4v __attribute__((ext_vector_type(4)));

__device__ __forceinline__ float fast_tanh(float z) {
    float e = __expf(2.f * z);
    return 1.f - 2.f / (e + 1.f);
}
__device__ __forceinline__ unsigned cvt_pk_bf16(float lo, float hi) {
    unsigned r;
    asm("v_cvt_pk_bf16_f32 %0, %1, %2" : "=v"(r) : "v"(lo), "v"(hi));
    return r;
}
__device__ __forceinline__ s8v pack8(float4 w0, float4 w1) {
    union { unsigned u[4]; s8v v; } r;
    r.u[0] = cvt_pk_bf16(w0.x, w0.y);
    r.u[1] = cvt_pk_bf16(w0.z, w0.w);
    r.u[2] = cvt_pk_bf16(w1.x, w1.y);
    r.u[3] = cvt_pk_bf16(w1.z, w1.w);
    return r.v;
}
__device__ __forceinline__ float bf2f(unsigned short h) {
    union { unsigned u; float f; } v; v.u = ((unsigned)h) << 16; return v.f;
}
__device__ __forceinline__ float bf_lo(unsigned w) {
    union { unsigned u; float f; } v; v.u = w << 16; return v.f;
}
__device__ __forceinline__ float bf_hi(unsigned w) {
    union { unsigned u; float f; } v; v.u = w & 0xffff0000u; return v.f;
}

// Cross-quad reduce then ONE atomic per address (128 ops, 1-way).
#define RFLUSH(ACC_, SEG_, DST_)                                              \
    if ((SEG_) >= 0) {                                                        \
        _Pragma("unroll")                                                     \
        for (int t = 0; t < 8; ++t) {                                         \
            ACC_[t] += __shfl_xor(ACC_[t], 16);                               \
            ACC_[t] += __shfl_xor(ACC_[t], 32);                               \
        }                                                                     \
        _Pragma("unroll")                                                     \
        for (int t = 0; t < 8; ++t)                                           \
            if ((t >> 1) == quad)                                             \
                atomicAdd(&(DST_)[(size_t)(SEG_) * 128 + m15 + 16 * t], ACC_[t]); \
    }

// Phase A epilogue for one C-row-group RG_: x read from wave-private LDS,
// y = x*(1+tanh(z)), y -> x2s bf16 (coalesced uint4), y bucketed.
#define EPI0(RG_)                                                             \
    {                                                                         \
        int r = R + quad * 4 + RG_;                                           \
        int seg = batch[r];                                                   \
        float yv[8];                                                          \
        _Pragma("unroll")                                                     \
        for (int t = 0; t < 8; ++t) {                                         \
            float xf = bf2f(xw[(quad * 4 + RG_) * 136 + m15 + 16 * t]);       \
            float z = af[t][RG_] + b2l[t];                                    \
            yv[t] = xf * (1.f + fast_tanh(z));                                \
        }                                                                     \
        union { unsigned u[4]; uint4 q; } pk;                                 \
        pk.u[0] = cvt_pk_bf16(yv[0], yv[1]);                                  \
        pk.u[1] = cvt_pk_bf16(yv[2], yv[3]);                                  \
        pk.u[2] = cvt_pk_bf16(yv[4], yv[5]);                                  \
        pk.u[3] = cvt_pk_bf16(yv[6], yv[7]);                                  \
        ((uint4*)x2s)[(size_t)b * 256 + RG_ * 64 + lane] = pk.q;              \
        if (seg == segLo) {                                                   \
            _Pragma("unroll")                                                 \
            for (int t = 0; t < 8; ++t) tl[t] += yv[t];                       \
        } else if (seg == segHi) {                                            \
            _Pragma("unroll")                                                 \
            for (int t = 0; t < 8; ++t) th[t] += yv[t];                       \
        } else {                                                              \
            _Pragma("unroll")                                                 \
            for (int t = 0; t < 8; ++t)                                       \
                atomicAdd(&sums[(size_t)seg * 128 + m15 + 16 * t], yv[t]);    \
        }                                                                     \
    }

// Phase A: x2 = x*(1+tanh(MLP(x))); wave-level segment sums; x2 cached bf16.
// (unchanged from R6 — known-good, ~131 us, no spill)
__global__ __launch_bounds__(THREADS, 3) void phaseA(
    const float* __restrict__ x, const int* __restrict__ batch,
    const float* __restrict__ fc1_w, const float* __restrict__ fc1_b,
    const float* __restrict__ fc2_w, const float* __restrict__ fc2_b,
    float* __restrict__ sums, unsigned short* __restrict__ x2s, int N)
{
    __shared__ unsigned short xbf[4][16 * 136]; // bf16 x rows, pitch 136, wave-private
    __shared__ s8v wB1[2][4][64];               // GEMM1 B-fragments, 8 KB
    __shared__ s8v wB2[8][64];                  // GEMM2 B-fragments, 8 KB
    __shared__ float hbuf[4][16 * 36];          // f32 hidden, pitch 36, wave-private

    const int lane = threadIdx.x & 63;
    const int wv = threadIdx.x >> 6;
    const int m15 = lane & 15;
    const int quad = lane >> 4;

    if (wv == 0) {
        #pragma unroll
        for (int t = 0; t < 2; ++t)
            #pragma unroll
            for (int kc = 0; kc < 4; ++kc) {
                const float* p = fc1_w + (16 * t + m15) * 128 + kc * 32 + quad * 8;
                wB1[t][kc][lane] = pack8(*(const float4*)p, *(const float4*)(p + 4));
            }
        #pragma unroll
        for (int t = 0; t < 8; ++t) {
            const float* p = fc2_w + (16 * t + m15) * 32 + quad * 8;
            wB2[t][lane] = pack8(*(const float4*)p, *(const float4*)(p + 4));
        }
    }
    float b1l[2], b2l[8];
    #pragma unroll
    for (int t = 0; t < 2; ++t) b1l[t] = fc1_b[m15 + 16 * t];
    #pragma unroll
    for (int t = 0; t < 8; ++t) b2l[t] = fc2_b[m15 + 16 * t];
    __syncthreads();

    const int total16 = N >> 4;
    const int nw = BLOCKS_A * 4;
    const int gw = blockIdx.x * 4 + wv;
    const int base = total16 / nw, rem = total16 % nw;
    const int b0 = gw * base + (gw < rem ? gw : rem);
    const int b1e = b0 + base + (gw < rem ? 1 : 0);

    unsigned short* xw = xbf[wv];
    float* hw = hbuf[wv];

    float accW[8];
    #pragma unroll
    for (int t = 0; t < 8; ++t) accW[t] = 0.f;
    int curW = -1;
    const f4v z4 = {0.f, 0.f, 0.f, 0.f};

    float4 L[8];
    if (b0 < b1e) {
        const float* xp = x + (size_t)(b0 << 4) * D;
        #pragma unroll
        for (int u = 0; u < 8; ++u)
            L[u] = *(const float4*)(xp + u * 256 + lane * 4);
    }

    for (int b = b0; b < b1e; ++b) {
        const int R = b << 4;
        uint2 P[8];
        #pragma unroll
        for (int u = 0; u < 8; ++u) {
            P[u].x = cvt_pk_bf16(L[u].x, L[u].y);
            P[u].y = cvt_pk_bf16(L[u].z, L[u].w);
        }
        if (b + 1 < b1e) {
            const float* xp = x + (size_t)((b + 1) << 4) * D;
            #pragma unroll
            for (int u = 0; u < 8; ++u)
                L[u] = *(const float4*)(xp + u * 256 + lane * 4);
        }
        #pragma unroll
        for (int u = 0; u < 8; ++u) {
            int row = 2 * u + (lane >> 5);
            int col = (lane & 31) * 4;
            *(uint2*)&xw[row * 136 + col] = P[u];
        }
        s8v ax[4];
        #pragma unroll
        for (int kc = 0; kc < 4; ++kc)
            ax[kc] = *(const s8v*)&xw[m15 * 136 + kc * 32 + quad * 8];
        f4v accH[2];
        accH[0] = z4; accH[1] = z4;
        #pragma unroll
        for (int kc = 0; kc < 4; ++kc) {
            accH[0] = __builtin_amdgcn_mfma_f32_16x16x32_bf16(ax[kc], wB1[0][kc][lane], accH[0], 0, 0, 0);
            accH[1] = __builtin_amdgcn_mfma_f32_16x16x32_bf16(ax[kc], wB1[1][kc][lane], accH[1], 0, 0, 0);
        }
        #pragma unroll
        for (int t = 0; t < 2; ++t)
            #pragma unroll
            for (int rg = 0; rg < 4; ++rg) {
                float hv = fmaxf(accH[t][rg] + b1l[t], 0.f);
                hw[(quad * 4 + rg) * 36 + m15 + 16 * t] = hv;
            }
        const f4v h0 = *(const f4v*)&hw[m15 * 36 + quad * 8];
        const f4v h1 = *(const f4v*)&hw[m15 * 36 + quad * 8 + 4];
        union { unsigned u[4]; s8v v; } ahu;
        ahu.u[0] = cvt_pk_bf16(h0[0], h0[1]);
        ahu.u[1] = cvt_pk_bf16(h0[2], h0[3]);
        ahu.u[2] = cvt_pk_bf16(h1[0], h1[1]);
        ahu.u[3] = cvt_pk_bf16(h1[2], h1[3]);
        s8v ah = ahu.v;
        f4v af[8];
        #pragma unroll
        for (int t = 0; t < 8; ++t)
            af[t] = __builtin_amdgcn_mfma_f32_16x16x32_bf16(ah, wB2[t][lane], z4, 0, 0, 0);

        const int segLo = batch[R];
        const int segHi = batch[R + 15];
        float tl[8], th[8];
        #pragma unroll
        for (int t = 0; t < 8; ++t) { tl[t] = 0.f; th[t] = 0.f; }

        EPI0(0) EPI0(1) EPI0(2) EPI0(3)

        if (segLo == curW) {
            #pragma unroll
            for (int t = 0; t < 8; ++t) accW[t] += tl[t];
        } else {
            RFLUSH(accW, curW, sums)
            curW = segLo;
            #pragma unroll
            for (int t = 0; t < 8; ++t) accW[t] = tl[t];
        }
        if (segHi != segLo) {
            RFLUSH(accW, curW, sums)
            curW = segHi;
            #pragma unroll
            for (int t = 0; t < 8; ++t) accW[t] = th[t];
        }
    }
    RFLUSH(accW, curW, sums)
}

// Fused phase C+B: ONE WAVE PER SEGMENT. Each wave: binary-search its row
// range, compute its tg row in-register (mean @ Wm, L2-hot), then stream
// its x2 rows with double-buffered loads. No curT divergence, no tg memory
// roundtrip, no atomics (plain store: wave owns the whole out row), no out
// memset needed (every row written unconditionally).
__global__ __launch_bounds__(THREADS, 4) void phaseCB(
    const unsigned short* __restrict__ x2s, const int* __restrict__ batch,
    const float* __restrict__ sums, const float* __restrict__ Wm,
    float* __restrict__ out, int N, int B)
{
    __shared__ float lmean[4][D];
    __shared__ float ltg[4][D];

    const int lane = threadIdx.x & 63;
    const int wv = threadIdx.x >> 6;
    const int m15 = lane & 15;
    const int quad = lane >> 4;

    const int s = blockIdx.x * 4 + wv;
    if (s >= B) return;

    // row range of segment s (sorted batch)
    int lo = 0, hi = N;
    while (lo < hi) { int mid = (lo + hi) >> 1; if (batch[mid] < s) lo = mid + 1; else hi = mid; }
    int lo1 = lo, hi1 = N;
    while (lo1 < hi1) { int mid = (lo1 + hi1) >> 1; if (batch[mid] < s + 1) lo1 = mid + 1; else hi1 = mid; }
    const int rlo = lo, rhi = lo1;

    // ---- in-register phase B: tg row for segment s ----
    float invc = 1.f / fmaxf((float)(rhi - rlo), 1.f);
    lmean[wv][lane]      = sums[(size_t)s * 128 + lane] * invc;
    lmean[wv][lane + 64] = sums[(size_t)s * 128 + lane + 64] * invc;
    float a0 = 0.f, a1 = 0.f;
    #pragma unroll 8
    for (int k = 0; k < D; ++k) {
        float mk = lmean[wv][k];   // LDS broadcast
        a0 = fmaf(mk, Wm[(size_t)k * 128 + lane], a0);
        a1 = fmaf(mk, Wm[(size_t)k * 128 + lane + 64], a1);
    }
    ltg[wv][lane]      = fast_tanh(a0);
    ltg[wv][lane + 64] = fast_tanh(a1);
    float tgv[8];
    #pragma unroll
    for (int t = 0; t < 8; ++t) tgv[t] = ltg[wv][m15 + 16 * t];  // dot-order gather

    // ---- stream rows [rlo, rhi): 16-row tiles, edge rows masked ----
    float acc[8];
    #pragma unroll
    for (int t = 0; t < 8; ++t) acc[t] = 0.f;

    const int tb0 = rlo >> 4;
    const int tb1 = (rhi + 15) >> 4;

    uint4 P[4];
    if (tb0 < tb1) {
        const uint4* p = (const uint4*)x2s + (size_t)tb0 * 256 + lane;
        #pragma unroll
        for (int rg = 0; rg < 4; ++rg) P[rg] = p[rg * 64];
    }

    for (int b = tb0; b < tb1; ++b) {
        uint4 C[4];
        #pragma unroll
        for (int rg = 0; rg < 4; ++rg) C[rg] = P[rg];
        if (b + 1 < tb1) {
            const uint4* p = (const uint4*)x2s + (size_t)(b + 1) * 256 + lane;
            #pragma unroll
            for (int rg = 0; rg < 4; ++rg) P[rg] = p[rg * 64];
        }
        const int R = b << 4;
        #pragma unroll
        for (int rg = 0; rg < 4; ++rg) {
            const int row = R + quad * 4 + rg;
            float xv[8];
            xv[0] = bf_lo(C[rg].x); xv[1] = bf_hi(C[rg].x);
            xv[2] = bf_lo(C[rg].y); xv[3] = bf_hi(C[rg].y);
            xv[4] = bf_lo(C[rg].z); xv[5] = bf_hi(C[rg].z);
            xv[6] = bf_lo(C[rg].w); xv[7] = bf_hi(C[rg].w);
            float dot = 0.f;
            #pragma unroll
            for (int t = 0; t < 8; ++t) dot = fmaf(xv[t], tgv[t], dot);
            dot += __shfl_xor(dot, 1);
            dot += __shfl_xor(dot, 2);
            dot += __shfl_xor(dot, 4);
            dot += __shfl_xor(dot, 8);
            float coef = 1.f / (1.f + __expf(-dot));
            if (row >= rlo && row < rhi) {
                #pragma unroll
                for (int t = 0; t < 8; ++t) acc[t] = fmaf(coef, xv[t], acc[t]);
            }
        }
    }

    // cross-quad reduce, plain store (wave owns the row)
    #pragma unroll
    for (int t = 0; t < 8; ++t) {
        acc[t] += __shfl_xor(acc[t], 16);
        acc[t] += __shfl_xor(acc[t], 32);
    }
    #pragma unroll
    for (int t = 0; t < 8; ++t)
        if ((t >> 1) == quad)
            out[(size_t)s * 128 + m15 + 16 * t] = acc[t];
}

extern "C" void kernel_launch(void* const* d_in, const int* in_sizes, int n_in,
                              void* d_out, int out_size, void* d_ws, size_t ws_size,
                              hipStream_t stream) {
    const float* x     = (const float*)d_in[0];
    const int*   batch = (const int*)d_in[1];
    const float* Wm    = (const float*)d_in[3];
    const float* fc1_w = (const float*)d_in[4];
    const float* fc1_b = (const float*)d_in[5];
    const float* fc2_w = (const float*)d_in[6];
    const float* fc2_b = (const float*)d_in[7];
    float* out = (float*)d_out;

    int N = in_sizes[0] / D;
    int B = out_size / D;

    float* sums = (float*)d_ws;                                   // [B,128]
    unsigned short* x2s = (unsigned short*)(sums + (size_t)B * D); // [N,128] bf16

    // only sums needs zeroing (phase A atomics); out fully overwritten by phaseCB
    hipMemsetAsync(d_ws, 0, (size_t)B * D * sizeof(float), stream);

    phaseA<<<BLOCKS_A, THREADS, 0, stream>>>(
        x, batch, fc1_w, fc1_b, fc2_w, fc2_b, sums, x2s, N);
    phaseCB<<<(B + 3) / 4, THREADS, 0, stream>>>(
        x2s, batch, sums, Wm, out, N, B);
}